// Round 14
// baseline (184.678 us; speedup 1.0000x reference)
//
#include <hip/hip_runtime.h>
#include <cmath>

typedef __attribute__((ext_vector_type(8))) short short8;
typedef __attribute__((ext_vector_type(4))) float f32x4;
typedef __attribute__((ext_vector_type(16))) float f32x16;
using u16 = unsigned short;

#define DEV static __device__ __forceinline__

DEV u16 f2bf(float f) {
  union { float f; unsigned u; } v; v.f = f;
  unsigned r = v.u + 0x7FFFu + ((v.u >> 16) & 1u);   // RNE
  return (u16)(r >> 16);
}

DEV unsigned cvtpk(float lo, float hi_) {            // low half = lo, high half = hi_
  unsigned d;
  asm("v_cvt_pk_bf16_f32 %0, %1, %2" : "=v"(d) : "v"(lo), "v"(hi_));
  return d;
}

DEV void gld16(const void* g, void* l) {             // async global->LDS, 16B/lane
  __builtin_amdgcn_global_load_lds(
      (const __attribute__((address_space(1))) unsigned*)g,
      (__attribute__((address_space(3))) unsigned*)l, 16, 0, 0);
}

DEV float hw_exp(float x) {                          // raw v_exp_f32, hazard-padded
  float y;                                           // (R10-proven form; do NOT batch —
  asm volatile("v_exp_f32 %0, %1\n\ts_nop 1"         //  R11's 4-per-asm blob cost +16us)
               : "=v"(y) : "v"(x));
  return y;
}

// ------ fp32 -> bf16 elementwise (8 elems/thread), z selects stream; + exp probe -----
__global__ __launch_bounds__(256) void conv_f32_bf16(const float* __restrict__ s0,
                                                     const float* __restrict__ s1,
                                                     u16* __restrict__ d0,
                                                     u16* __restrict__ d1, int n8,
                                                     float* __restrict__ scale_out) {
  const float* src = blockIdx.z ? s1 : s0;
  u16* dst = blockIdx.z ? d1 : d0;
  int i = blockIdx.x * 256 + threadIdx.x;
  if (i < n8) {
    const float4* s = reinterpret_cast<const float4*>(src) + (size_t)i * 2;
    float4 a = s[0], b = s[1];
    union { u16 s[8]; uint4 v; } t;
    t.s[0]=f2bf(a.x); t.s[1]=f2bf(a.y); t.s[2]=f2bf(a.z); t.s[3]=f2bf(a.w);
    t.s[4]=f2bf(b.x); t.s[5]=f2bf(b.y); t.s[6]=f2bf(b.z); t.s[7]=f2bf(b.w);
    reinterpret_cast<uint4*>(dst)[i] = t.v;
  }
  if (blockIdx.x == 0 && blockIdx.z == 0 && threadIdx.x == 0) {
    float one;
    asm volatile("v_mov_b32 %0, 1.0" : "=v"(one));
    float bb = hw_exp(one);
    float lnb = logf(bb);
    bool ok = (fabsf(bb - 2.0f) < 0.25f) && (lnb > 0.1f);
    const float xs[3] = {0.3333f, -5.7f, 9.1f};
    for (int k = 0; k < 3; ++k) {
      float xo;
      asm volatile("v_mov_b32 %0, %1" : "=v"(xo) : "v"(xs[k]));
      float yn = hw_exp(xo);
      float yr = expf(lnb * xs[k]);
      ok = ok && (fabsf(yn - yr) <= 2e-4f * fabsf(yr));
    }
    scale_out[0] = ok ? (0.125f / lnb) : (0.125f / 0.69314718056f);
    scale_out[1] = ok ? 1.0f : 0.0f;
  }
}

// --- fp32 [R][C] -> bf16 [C][R], all 4 weight matrices in one launch (z selects) ----
__global__ __launch_bounds__(256) void transpose_w(
    const float* __restrict__ q1, const float* __restrict__ q2,
    const float* __restrict__ o1, const float* __restrict__ o2,
    u16* __restrict__ q1t, u16* __restrict__ q2t,
    u16* __restrict__ o1t, u16* __restrict__ o2t,
    const float* __restrict__ scale) {
  const int z = blockIdx.z;
  const float* src; u16* dst; int C, qcols;
  if (z == 0)      { src = q1; dst = q1t; C = 3072; qcols = 1024; }
  else if (z == 1) { src = q2; dst = q2t; C = 3072; qcols = 1024; }
  else if (z == 2) { src = o1; dst = o1t; C = 1024; qcols = 0; }
  else             { src = o2; dst = o2t; C = 1024; qcols = 0; }
  const int R = 1024;
  int cb = blockIdx.x * 32;
  if (cb >= C) return;
  const float qscale = scale[0];
  __shared__ float tile[32][33];
  int tx = threadIdx.x & 31, ty = threadIdx.x >> 5;  // 32 x 8
  int rb = blockIdx.y * 32;
#pragma unroll
  for (int j = 0; j < 32; j += 8)
    tile[ty + j][tx] = src[(size_t)(rb + ty + j) * C + cb + tx];
  __syncthreads();
#pragma unroll
  for (int j = 0; j < 32; j += 8) {
    int c = cb + ty + j;
    float sc = (c < qcols) ? qscale : 1.0f;
    dst[(size_t)c * R + rb + tx] = f2bf(tile[tx][ty + j] * sc);
  }
}

// ------- 256x192 4-phase GEMM for qkv: grid 512 = EXACTLY 2 full CU rounds ----------
// 8 waves (2M x 4N), per-wave 128x48 (acc[8][3]), BK=64, dbuf 112KB LDS. Stage ops (7)
// front-loaded into phases 0-1; tile-boundary drain keeps 2-phase slack.
// V-cols (>=2048) -> vT transposed.
extern __shared__ char dsmem[];
#define GBUF 57344   // 32KB A + 24KB B per buffer

__global__ __launch_bounds__(512, 2) void gemm256(
    const u16* __restrict__ A0, const u16* __restrict__ A1,
    const u16* __restrict__ B0, const u16* __restrict__ B1,
    u16* __restrict__ Q0, u16* __restrict__ Q1,
    u16* __restrict__ V0, u16* __restrict__ V1) {
  const int orig = blockIdx.x;
  const int wgid = (orig & 7) * 64 + (orig >> 3);    // XCD swizzle (512 % 8 == 0)
  const int z = wgid / 256, rr_ = wgid % 256;
  const int bx = rr_ / 16, by = rr_ % 16;
  const u16* Ag = z ? A1 : A0;
  const u16* Bg = z ? B1 : B0;
  const size_t m0 = (size_t)bx * 256, n0 = (size_t)by * 192;
  const int K = 1024;

  const int tid = threadIdx.x;
  const int lane = tid & 63;
  const int wave = tid >> 6;
  const int wm = wave >> 2, wn = wave & 3;   // 2 x 4; per-wave 128M x 48N
  const int lr = lane & 15, lk = lane >> 4;

  f32x4 acc[8][3] = {};

  auto STG = [&](int buf, int kt, int opi) {
    int idx = opi * 512 + tid;
    char* base = dsmem + buf * GBUF;
    if (idx < 2048) {
      int r = idx >> 3, c = idx & 7;
      gld16(Ag + (m0 + r) * (size_t)K + kt * 64 + ((c ^ (r & 7)) * 8), base + idx * 16);
    } else {
      int j = idx - 2048;
      int r = j >> 3, c = j & 7;
      gld16(Bg + (n0 + r) * (size_t)K + kt * 64 + ((c ^ (r & 7)) * 8), base + 32768 + j * 16);
    }
  };
  auto DSA = [&](short8* af, int buf, int mg, int kh) {
#pragma unroll
    for (int i = 0; i < 4; ++i) {
      int row = wm * 128 + (mg * 4 + i) * 16 + lr;
      af[i] = *reinterpret_cast<const short8*>(
          dsmem + buf * GBUF + row * 128 + (((kh * 4 + lk) ^ (row & 7)) * 16));
    }
  };
  auto DSB = [&](short8* bf_, int buf, int kh) {
#pragma unroll
    for (int j = 0; j < 3; ++j) {
      int row = wn * 48 + j * 16 + lr;
      bf_[j] = *reinterpret_cast<const short8*>(
          dsmem + buf * GBUF + 32768 + row * 128 + (((kh * 4 + lk) ^ (row & 7)) * 16));
    }
  };

#pragma unroll
  for (int o = 0; o < 7; ++o) STG(0, 0, o);
  asm volatile("s_waitcnt vmcnt(0)" ::: "memory");
  __syncthreads();

  int cur = 0;
  for (int kt = 0; kt < 16; ++kt) {
    short8 af[4], bf_[3];
    const int more = (kt < 15);

    // ---- phase 0: (kh0, mg0); stage ops 0-3
    DSA(af, cur, 0, 0); DSB(bf_, cur, 0);
    if (more) { STG(cur ^ 1, kt + 1, 0); STG(cur ^ 1, kt + 1, 1);
                STG(cur ^ 1, kt + 1, 2); STG(cur ^ 1, kt + 1, 3); }
    __builtin_amdgcn_s_barrier();
    asm volatile("s_waitcnt lgkmcnt(0)" ::: "memory");
    __builtin_amdgcn_sched_barrier(0);
    __builtin_amdgcn_s_setprio(1);
#pragma unroll
    for (int i = 0; i < 4; ++i)
#pragma unroll
      for (int j = 0; j < 3; ++j)
        acc[i][j] = __builtin_amdgcn_mfma_f32_16x16x32_bf16(af[i], bf_[j], acc[i][j], 0, 0, 0);
    __builtin_amdgcn_s_setprio(0);
    __builtin_amdgcn_s_barrier();

    // ---- phase 1: (kh0, mg1); B reused; stage ops 4-6
    DSA(af, cur, 1, 0);
    if (more) { STG(cur ^ 1, kt + 1, 4); STG(cur ^ 1, kt + 1, 5);
                STG(cur ^ 1, kt + 1, 6); }
    __builtin_amdgcn_s_barrier();
    asm volatile("s_waitcnt lgkmcnt(0)" ::: "memory");
    __builtin_amdgcn_sched_barrier(0);
    __builtin_amdgcn_s_setprio(1);
#pragma unroll
    for (int i = 0; i < 4; ++i)
#pragma unroll
      for (int j = 0; j < 3; ++j)
        acc[4 + i][j] = __builtin_amdgcn_mfma_f32_16x16x32_bf16(af[i], bf_[j], acc[4 + i][j], 0, 0, 0);
    __builtin_amdgcn_s_setprio(0);
    __builtin_amdgcn_s_barrier();

    // ---- phase 2: (kh1, mg0); no stage
    DSA(af, cur, 0, 1); DSB(bf_, cur, 1);
    __builtin_amdgcn_s_barrier();
    asm volatile("s_waitcnt lgkmcnt(0)" ::: "memory");
    __builtin_amdgcn_sched_barrier(0);
    __builtin_amdgcn_s_setprio(1);
#pragma unroll
    for (int i = 0; i < 4; ++i)
#pragma unroll
      for (int j = 0; j < 3; ++j)
        acc[i][j] = __builtin_amdgcn_mfma_f32_16x16x32_bf16(af[i], bf_[j], acc[i][j], 0, 0, 0);
    __builtin_amdgcn_s_setprio(0);
    __builtin_amdgcn_s_barrier();

    // ---- phase 3: (kh1, mg1); tile-boundary drain (youngest load 2 phases old)
    DSA(af, cur, 1, 1);
    __builtin_amdgcn_s_barrier();
    asm volatile("s_waitcnt lgkmcnt(0)" ::: "memory");
    __builtin_amdgcn_sched_barrier(0);
    __builtin_amdgcn_s_setprio(1);
#pragma unroll
    for (int i = 0; i < 4; ++i)
#pragma unroll
      for (int j = 0; j < 3; ++j)
        acc[4 + i][j] = __builtin_amdgcn_mfma_f32_16x16x32_bf16(af[i], bf_[j], acc[4 + i][j], 0, 0, 0);
    __builtin_amdgcn_s_setprio(0);
    asm volatile("s_waitcnt vmcnt(0)" ::: "memory");
    __builtin_amdgcn_s_barrier();
    cur ^= 1;
  }

  // epilogue: per-frag (16-aligned, wave-uniform) branch: Q/K cols -> qkv row-major;
  // V cols (>=2048) -> vT col-major.
  const int row0 = (int)m0 + wm * 128;
  const int col0 = (int)n0 + wn * 48;
  u16* Qo = z ? Q1 : Q0;
  u16* Vo = z ? V1 : V0;
#pragma unroll
  for (int nf = 0; nf < 3; ++nf) {
    int colf = col0 + nf * 16;          // frag col base, multiple of 16
    if (colf < 2048) {
      int col = colf + lr;
#pragma unroll
      for (int mf = 0; mf < 8; ++mf)
#pragma unroll
        for (int g = 0; g < 4; ++g) {
          int row = row0 + mf * 16 + lk * 4 + g;
          Qo[(size_t)row * 3072 + col] = f2bf(acc[mf][nf][g]);
        }
    } else {
      int col = colf + lr;
#pragma unroll
      for (int mf = 0; mf < 8; ++mf) {
        int row = row0 + mf * 16 + lk * 4;
        size_t vbase = ((size_t)((row >> 11) * 1024 + (col - 2048))) * 2048 + (row & 2047);
        union { u16 s[4]; unsigned long long v; } pk;
#pragma unroll
        for (int g = 0; g < 4; ++g) pk.s[g] = f2bf(acc[mf][nf][g]);
        *reinterpret_cast<unsigned long long*>(Vo + vbase) = pk.v;
      }
    }
  }
}

// ---- out-proj GEMM: 256x128 tiles, grid 256 = EXACTLY 1 CU round, fp32+bias out ----
__global__ __launch_bounds__(512, 2) void gemm_op(
    const u16* __restrict__ A0, const u16* __restrict__ A1,
    const u16* __restrict__ B0, const u16* __restrict__ B1,
    float* __restrict__ C0, float* __restrict__ C1,
    const float* __restrict__ b0_, const float* __restrict__ b1_) {
  const int orig = blockIdx.x;
  const int wgid = (orig & 7) * 32 + (orig >> 3);    // XCD swizzle (256 % 8 == 0)
  const int z = wgid / 128, rr_ = wgid % 128;
  const int bx = rr_ / 8, by = rr_ % 8;
  const u16* Ag = z ? A1 : A0;
  const u16* Bg = z ? B1 : B0;
  float* Cf = z ? C1 : C0;
  const float* bias = z ? b1_ : b0_;
  const size_t m0 = (size_t)bx * 256, n0 = (size_t)by * 128;
  const int K = 1024;

  const int tid = threadIdx.x;
  const int lane = tid & 63;
  const int wave = tid >> 6;
  const int wm = wave >> 1, wn = wave & 1;   // 4 x 2
  const int lr = lane & 15, lk = lane >> 4;

  f32x4 acc[4][4] = {};

  auto STG = [&](int buf, int kt, int opi) {
    int idx = opi * 512 + tid;
    char* base = dsmem + buf * 49152;
    if (idx < 2048) {
      int r = idx >> 3, c = idx & 7;
      gld16(Ag + (m0 + r) * (size_t)K + kt * 64 + ((c ^ (r & 7)) * 8), base + idx * 16);
    } else {
      int j = idx - 2048;
      int r = j >> 3, c = j & 7;
      gld16(Bg + (n0 + r) * (size_t)K + kt * 64 + ((c ^ (r & 7)) * 8), base + 32768 + j * 16);
    }
  };
  auto DSA = [&](short8* af, int buf, int kh) {
#pragma unroll
    for (int i = 0; i < 4; ++i) {
      int row = wm * 64 + i * 16 + lr;
      af[i] = *reinterpret_cast<const short8*>(
          dsmem + buf * 49152 + row * 128 + (((kh * 4 + lk) ^ (row & 7)) * 16));
    }
  };
  auto DSB = [&](short8* bf_, int buf, int kh) {
#pragma unroll
    for (int j = 0; j < 4; ++j) {
      int row = wn * 64 + j * 16 + lr;
      bf_[j] = *reinterpret_cast<const short8*>(
          dsmem + buf * 49152 + 32768 + row * 128 + (((kh * 4 + lk) ^ (row & 7)) * 16));
    }
  };

#pragma unroll
  for (int o = 0; o < 6; ++o) STG(0, 0, o);
  asm volatile("s_waitcnt vmcnt(0)" ::: "memory");
  __syncthreads();

  int cur = 0;
  for (int kt = 0; kt < 16; ++kt) {
    short8 af[4], bf_[4];
    const int more = (kt < 15);

    // ---- phase 0 (kh0); stage ALL 6 next-tile ops
    DSA(af, cur, 0); DSB(bf_, cur, 0);
    if (more) { STG(cur ^ 1, kt + 1, 0); STG(cur ^ 1, kt + 1, 1); STG(cur ^ 1, kt + 1, 2);
                STG(cur ^ 1, kt + 1, 3); STG(cur ^ 1, kt + 1, 4); STG(cur ^ 1, kt + 1, 5); }
    __builtin_amdgcn_s_barrier();
    asm volatile("s_waitcnt lgkmcnt(0)" ::: "memory");
    __builtin_amdgcn_sched_barrier(0);
    __builtin_amdgcn_s_setprio(1);
#pragma unroll
    for (int i = 0; i < 4; ++i)
#pragma unroll
      for (int j = 0; j < 4; ++j)
        acc[i][j] = __builtin_amdgcn_mfma_f32_16x16x32_bf16(af[i], bf_[j], acc[i][j], 0, 0, 0);
    __builtin_amdgcn_s_setprio(0);
    __builtin_amdgcn_s_barrier();

    // ---- phase 1 (kh1); no stage; end-of-tile drain (loads ~1 full phase old)
    DSA(af, cur, 1); DSB(bf_, cur, 1);
    __builtin_amdgcn_s_barrier();
    asm volatile("s_waitcnt lgkmcnt(0)" ::: "memory");
    __builtin_amdgcn_sched_barrier(0);
    __builtin_amdgcn_s_setprio(1);
#pragma unroll
    for (int i = 0; i < 4; ++i)
#pragma unroll
      for (int j = 0; j < 4; ++j)
        acc[i][j] = __builtin_amdgcn_mfma_f32_16x16x32_bf16(af[i], bf_[j], acc[i][j], 0, 0, 0);
    __builtin_amdgcn_s_setprio(0);
    asm volatile("s_waitcnt vmcnt(0)" ::: "memory");
    __builtin_amdgcn_s_barrier();
    cur ^= 1;
  }

  const int row0 = (int)m0 + wm * 64;
  const int col0 = (int)n0 + wn * 64;
#pragma unroll
  for (int nf = 0; nf < 4; ++nf) {
    int col = col0 + nf * 16 + lr;
    float bv = bias[col];
#pragma unroll
    for (int mf = 0; mf < 4; ++mf)
#pragma unroll
      for (int g = 0; g < 4; ++g) {
        int row = row0 + mf * 16 + lk * 4 + g;
        Cf[(size_t)row * 1024 + col] = acc[mf][nf][g] + bv;
      }
  }
}

// -------- flash attention: swapped 32x32, static-max, q64/wave, KVBLK=128 ------------
// R10 per-sub-tile body unchanged; KV tile doubled to 128 (two 64-kv sub-tiles per
// barrier pair) -> barriers and DMA-drain stalls halve (32 -> 16 iterations).
// Dynamic LDS 64.3KB: per buffer K0|K1 (16KB) + V0|V1 (16KB), same [64][128B] swizzled
// sub-tile layout as R13 so all fragment math is identical.
#define FKOFF0 0
#define FVOFF0 (16384 + 64)
#define FKOFF1 (32768 + 128)
#define FVOFF1 (FKOFF1 + 16384 + 64)
#define FSMEM  (FVOFF1 + 16384)          // 65728

__global__ __launch_bounds__(256, 2) void flash(
    const u16* __restrict__ qkv1, const u16* __restrict__ qkv2,
    const u16* __restrict__ vT1, const u16* __restrict__ vT2,
    u16* __restrict__ ao1, u16* __restrict__ ao2,
    const float* __restrict__ sflag) {
  const int bid = blockIdx.x;
  const int bh_dir = bid & 63;        // XCD selector: bid%8 fixed per (dir,bh)
  const int qt = bid >> 6;            // 0..7 (256 q-rows per block)
  const int dir = bh_dir >> 5;
  const int bh = bh_dir & 31;         // b*16+h
  const int b = bh >> 4, h = bh & 15;
  const u16* qkvQ  = dir ? qkv1 : qkv2;
  const u16* qkvKV = dir ? qkv2 : qkv1;
  const u16* vT    = dir ? vT2 : vT1;
  u16* Oout        = dir ? ao2 : ao1;

  const bool nat = (sflag[1] != 0.0f);   // wave-uniform
  char* smem = dsmem;

  const int tid = threadIdx.x;
  const int lane = tid & 63, wave = tid >> 6;
  const int l31 = lane & 31, hi = lane >> 5;

  const int qbase = qt * 256 + wave * 64;
  const u16* qp0 = qkvQ + (size_t)(b * 2048 + qbase + l31) * 3072 + h * 64 + hi * 8;
  const u16* qp1 = qp0 + (size_t)32 * 3072;
  short8 qf0[4], qf1[4];
#pragma unroll
  for (int c = 0; c < 4; ++c) {
    qf0[c] = *reinterpret_cast<const short8*>(qp0 + c * 16);
    qf1[c] = *reinterpret_cast<const short8*>(qp1 + c * 16);
  }

  // stage 128 kv rows of K (1024 chunks) + 128 kv cols of V as two [64][64] sub-tiles
  auto STAGE = [&](char* kb, char* vb, int kv0) {
#pragma unroll
    for (int i = 0; i < 4; ++i) {
      int idx = tid + i * 256;
      int r = idx >> 3, c = idx & 7, cs = c ^ (r & 7);
      gld16(qkvKV + (size_t)(b * 2048 + kv0 + r) * 3072 + 1024 + h * 64 + cs * 8, kb + idx * 16);
      int sub = idx >> 9, j = idx & 511;
      int rv = j >> 3, cv = j & 7, csv = cv ^ (rv & 7);
      gld16(vT + (size_t)(bh * 64 + rv) * 2048 + kv0 + sub * 64 + csv * 8, vb + idx * 16);
    }
  };

  auto EXPV = [&](f32x16& S) {
    if (nat) {
#pragma unroll
      for (int r = 0; r < 16; ++r) S[r] = hw_exp(S[r]);
    } else {
#pragma unroll
      for (int r = 0; r < 16; ++r) S[r] = __builtin_exp2f(S[r]);
    }
  };

  short8 ones;                        // bf16 1.0 for the l-sum MFMA
#pragma unroll
  for (int j = 0; j < 8; ++j) ones[j] = (short)0x3F80;

  f32x16 oA0 = {}, oA1 = {}, oB0 = {}, oB1 = {}, laccA = {}, laccB = {};

  STAGE(smem + FKOFF0, smem + FVOFF0, 0);

  union U8 { unsigned u[4]; short8 s8; };

  for (int t = 0; t < 16; ++t) {
    char* Ks = smem + ((t & 1) ? FKOFF1 : FKOFF0);
    char* Vs = smem + ((t & 1) ? FVOFF1 : FVOFF0);
    __syncthreads();                  // drains own DMA for buf(t); all quarters visible
    if (t < 15)
      STAGE(smem + ((t & 1) ? FKOFF0 : FKOFF1), smem + ((t & 1) ? FVOFF0 : FVOFF1),
            (t + 1) * 128);

#pragma unroll
    for (int sub = 0; sub < 2; ++sub) {
      char* Kss = Ks + sub * 8192;
      char* Vss = Vs + sub * 8192;

      // K frags (8 reads, reused by both q-sets). A-operand: m=kv, k=d
      short8 kf[8];
#pragma unroll
      for (int c = 0; c < 4; ++c) {
        int sw = ((c * 2 + hi) ^ (l31 & 7)) * 16;
        kf[c]     = *reinterpret_cast<const short8*>(Kss + l31 * 128 + sw);
        kf[c + 4] = *reinterpret_cast<const short8*>(Kss + (32 + l31) * 128 + sw);
      }

      // QK set0
      f32x16 sA0 = {}, sA1 = {};
#pragma unroll
      for (int c = 0; c < 4; ++c) {
        sA0 = __builtin_amdgcn_mfma_f32_32x32x16_bf16(kf[c],     qf0[c], sA0, 0, 0, 0);
        sA1 = __builtin_amdgcn_mfma_f32_32x32x16_bf16(kf[c + 4], qf0[c], sA1, 0, 0, 0);
      }
      EXPV(sA0); EXPV(sA1);
      short8 paA[4];
#pragma unroll
      for (int kc = 0; kc < 4; ++kc) {
        const f32x16& S = (kc < 2) ? sA0 : sA1;
        int rb = (kc & 1) * 8;
        unsigned a0 = cvtpk(S[rb + 0], S[rb + 1]);
        unsigned b0 = cvtpk(S[rb + 4], S[rb + 5]);
        asm volatile("v_permlane32_swap_b32 %0, %1" : "+v"(a0), "+v"(b0));
        unsigned a1 = cvtpk(S[rb + 2], S[rb + 3]);
        unsigned b1 = cvtpk(S[rb + 6], S[rb + 7]);
        asm volatile("v_permlane32_swap_b32 %0, %1" : "+v"(a1), "+v"(b1));
        U8 u; u.u[0] = a0; u.u[1] = a1; u.u[2] = b0; u.u[3] = b1;
        paA[kc] = u.s8;
      }

      // QK set1 (kf reused, then dead)
      f32x16 sB0 = {}, sB1 = {};
#pragma unroll
      for (int c = 0; c < 4; ++c) {
        sB0 = __builtin_amdgcn_mfma_f32_32x32x16_bf16(kf[c],     qf1[c], sB0, 0, 0, 0);
        sB1 = __builtin_amdgcn_mfma_f32_32x32x16_bf16(kf[c + 4], qf1[c], sB1, 0, 0, 0);
      }

      // V frags (8 reads, reused by both q-sets). B-operand: n=d, k=kv
      short8 vf[8];
#pragma unroll
      for (int kc = 0; kc < 4; ++kc) {
        int sw = ((kc * 2 + hi) ^ (l31 & 7)) * 16;
        vf[kc]     = *reinterpret_cast<const short8*>(Vss + l31 * 128 + sw);
        vf[kc + 4] = *reinterpret_cast<const short8*>(Vss + (32 + l31) * 128 + sw);
      }

      EXPV(sB0); EXPV(sB1);
      short8 paB[4];
#pragma unroll
      for (int kc = 0; kc < 4; ++kc) {
        const f32x16& S = (kc < 2) ? sB0 : sB1;
        int rb = (kc & 1) * 8;
        unsigned a0 = cvtpk(S[rb + 0], S[rb + 1]);
        unsigned b0 = cvtpk(S[rb + 4], S[rb + 5]);
        asm volatile("v_permlane32_swap_b32 %0, %1" : "+v"(a0), "+v"(b0));
        unsigned a1 = cvtpk(S[rb + 2], S[rb + 3]);
        unsigned b1 = cvtpk(S[rb + 6], S[rb + 7]);
        asm volatile("v_permlane32_swap_b32 %0, %1" : "+v"(a1), "+v"(b1));
        U8 u; u.u[0] = a0; u.u[1] = a1; u.u[2] = b0; u.u[3] = b1;
        paB[kc] = u.s8;
      }

      // PV + l-sum (V frags reused across q-sets)
#pragma unroll
      for (int kc = 0; kc < 4; ++kc) {
        oA0 = __builtin_amdgcn_mfma_f32_32x32x16_bf16(paA[kc], vf[kc],     oA0, 0, 0, 0);
        oA1 = __builtin_amdgcn_mfma_f32_32x32x16_bf16(paA[kc], vf[kc + 4], oA1, 0, 0, 0);
        oB0 = __builtin_amdgcn_mfma_f32_32x32x16_bf16(paB[kc], vf[kc],     oB0, 0, 0, 0);
        oB1 = __builtin_amdgcn_mfma_f32_32x32x16_bf16(paB[kc], vf[kc + 4], oB1, 0, 0, 0);
        laccA = __builtin_amdgcn_mfma_f32_32x32x16_bf16(paA[kc], ones, laccA, 0, 0, 0);
        laccB = __builtin_amdgcn_mfma_f32_32x32x16_bf16(paB[kc], ones, laccB, 0, 0, 0);
      }
    }
  }

  // epilogue: lacc[r] = row-sum for output row crow(r,hi) -> no shuffles
  const int rowbase = b * 2048 + qt * 256 + wave * 64;
#pragma unroll
  for (int r = 0; r < 16; ++r) {
    int q = (r & 3) + 8 * (r >> 2) + 4 * hi;
    float liA = 1.0f / laccA[r], liB = 1.0f / laccB[r];
    u16* opA = Oout + (size_t)(rowbase + q) * 1024 + h * 64 + l31;
    u16* opB = opA + (size_t)32 * 1024;
    opA[0]  = f2bf(oA0[r] * liA);
    opA[32] = f2bf(oA1[r] * liA);
    opB[0]  = f2bf(oB0[r] * liB);
    opB[32] = f2bf(oB1[r] * liB);
  }
}

// ------------------------------- host -------------------------------
extern "C" void kernel_launch(void* const* d_in, const int* in_sizes, int n_in,
                              void* d_out, int out_size, void* d_ws, size_t ws_size,
                              hipStream_t stream) {
  const float* x1  = (const float*)d_in[0];
  const float* x2  = (const float*)d_in[1];
  const float* Wq1 = (const float*)d_in[2];
  const float* Wq2 = (const float*)d_in[3];
  const float* Wo1 = (const float*)d_in[4];
  const float* bo1 = (const float*)d_in[5];
  const float* Wo2 = (const float*)d_in[6];
  const float* bo2 = (const float*)d_in[7];
  float* out = (float*)d_out;

  char* ws = (char*)d_ws;
  u16* x1b  = (u16*)(ws + 0);            // 8.0 MB  [4096][1024]
  u16* x2b  = (u16*)(ws + 8388608);
  u16* Wq1t = (u16*)(ws + 16777216);     // 6.0 MB  [3072][1024]
  u16* Wq2t = (u16*)(ws + 23068672);
  u16* Wo1t = (u16*)(ws + 29360128);     // 2.0 MB  [1024][1024]
  u16* Wo2t = (u16*)(ws + 31457280);
  u16* qkv1 = (u16*)(ws + 33554432);     // 24 MB   [4096][3072] (V cols >=2048 unused)
  u16* qkv2 = (u16*)(ws + 58720256);
  u16* vT1  = (u16*)(ws + 83886080);     // 8.0 MB  [32*64][2048]
  u16* vT2  = (u16*)(ws + 92274688);
  u16* ao1  = (u16*)(ws + 100663296);    // 8.0 MB  [4096][1024]
  u16* ao2  = (u16*)(ws + 109051904);    // end: 117440512 (112 MB)

  // scale buffer in qkv1's never-written V-columns (row 0, cols 2048..):
  float* scale_buf = (float*)(qkv1 + 2048);

  hipFuncSetAttribute(reinterpret_cast<const void*>(gemm256),
                      hipFuncAttributeMaxDynamicSharedMemorySize, 114688);
  hipFuncSetAttribute(reinterpret_cast<const void*>(gemm_op),
                      hipFuncAttributeMaxDynamicSharedMemorySize, 98304);
  hipFuncSetAttribute(reinterpret_cast<const void*>(flash),
                      hipFuncAttributeMaxDynamicSharedMemorySize, FSMEM);

  conv_f32_bf16<<<dim3(2048, 1, 2), 256, 0, stream>>>(x1, x2, x1b, x2b, 4194304 / 8,
                                                      scale_buf);
  transpose_w<<<dim3(96, 32, 4), 256, 0, stream>>>(Wq1, Wq2, Wo1, Wo2,
                                                   Wq1t, Wq2t, Wo1t, Wo2t, scale_buf);

  gemm256<<<dim3(512), 512, 114688, stream>>>(x1b, x2b, Wq1t, Wq2t,
                                              qkv1, qkv2, vT1, vT2);

  flash<<<dim3(512), 256, FSMEM, stream>>>(qkv1, qkv2, vT1, vT2, ao1, ao2, scale_buf);

  gemm_op<<<dim3(256), 512, 98304, stream>>>(ao1, ao2, Wo1t, Wo2t,
                                             out, out + 4194304, bo1, bo2);
}

// Round 15
// 178.401 us; speedup vs baseline: 1.0352x; 1.0352x over previous
//
#include <hip/hip_runtime.h>
#include <cmath>

typedef __attribute__((ext_vector_type(8))) short short8;
typedef __attribute__((ext_vector_type(4))) float f32x4;
typedef __attribute__((ext_vector_type(16))) float f32x16;
using u16 = unsigned short;

#define DEV static __device__ __forceinline__

DEV u16 f2bf(float f) {
  union { float f; unsigned u; } v; v.f = f;
  unsigned r = v.u + 0x7FFFu + ((v.u >> 16) & 1u);   // RNE
  return (u16)(r >> 16);
}

DEV unsigned cvtpk(float lo, float hi_) {            // low half = lo, high half = hi_
  unsigned d;
  asm("v_cvt_pk_bf16_f32 %0, %1, %2" : "=v"(d) : "v"(lo), "v"(hi_));
  return d;
}

DEV void gld16(const void* g, void* l) {             // async global->LDS, 16B/lane
  __builtin_amdgcn_global_load_lds(
      (const __attribute__((address_space(1))) unsigned*)g,
      (__attribute__((address_space(3))) unsigned*)l, 16, 0, 0);
}

DEV float hw_exp(float x) {                          // raw v_exp_f32, hazard-padded
  float y;                                           // (R10-proven form; do NOT batch —
  asm volatile("v_exp_f32 %0, %1\n\ts_nop 1"         //  R11's 4-per-asm blob cost +16us)
               : "=v"(y) : "v"(x));
  return y;
}

// ------ fp32 -> bf16 elementwise (8 elems/thread), z selects stream; + exp probe -----
__global__ __launch_bounds__(256) void conv_f32_bf16(const float* __restrict__ s0,
                                                     const float* __restrict__ s1,
                                                     u16* __restrict__ d0,
                                                     u16* __restrict__ d1, int n8,
                                                     float* __restrict__ scale_out) {
  const float* src = blockIdx.z ? s1 : s0;
  u16* dst = blockIdx.z ? d1 : d0;
  int i = blockIdx.x * 256 + threadIdx.x;
  if (i < n8) {
    const float4* s = reinterpret_cast<const float4*>(src) + (size_t)i * 2;
    float4 a = s[0], b = s[1];
    union { u16 s[8]; uint4 v; } t;
    t.s[0]=f2bf(a.x); t.s[1]=f2bf(a.y); t.s[2]=f2bf(a.z); t.s[3]=f2bf(a.w);
    t.s[4]=f2bf(b.x); t.s[5]=f2bf(b.y); t.s[6]=f2bf(b.z); t.s[7]=f2bf(b.w);
    reinterpret_cast<uint4*>(dst)[i] = t.v;
  }
  if (blockIdx.x == 0 && blockIdx.z == 0 && threadIdx.x == 0) {
    float one;
    asm volatile("v_mov_b32 %0, 1.0" : "=v"(one));
    float bb = hw_exp(one);
    float lnb = logf(bb);
    bool ok = (fabsf(bb - 2.0f) < 0.25f) && (lnb > 0.1f);
    const float xs[3] = {0.3333f, -5.7f, 9.1f};
    for (int k = 0; k < 3; ++k) {
      float xo;
      asm volatile("v_mov_b32 %0, %1" : "=v"(xo) : "v"(xs[k]));
      float yn = hw_exp(xo);
      float yr = expf(lnb * xs[k]);
      ok = ok && (fabsf(yn - yr) <= 2e-4f * fabsf(yr));
    }
    scale_out[0] = ok ? (0.125f / lnb) : (0.125f / 0.69314718056f);
    scale_out[1] = ok ? 1.0f : 0.0f;
  }
}

// --- fp32 [R][C] -> bf16 [C][R], all 4 weight matrices in one launch (z selects) ----
__global__ __launch_bounds__(256) void transpose_w(
    const float* __restrict__ q1, const float* __restrict__ q2,
    const float* __restrict__ o1, const float* __restrict__ o2,
    u16* __restrict__ q1t, u16* __restrict__ q2t,
    u16* __restrict__ o1t, u16* __restrict__ o2t,
    const float* __restrict__ scale) {
  const int z = blockIdx.z;
  const float* src; u16* dst; int C, qcols;
  if (z == 0)      { src = q1; dst = q1t; C = 3072; qcols = 1024; }
  else if (z == 1) { src = q2; dst = q2t; C = 3072; qcols = 1024; }
  else if (z == 2) { src = o1; dst = o1t; C = 1024; qcols = 0; }
  else             { src = o2; dst = o2t; C = 1024; qcols = 0; }
  const int R = 1024;
  int cb = blockIdx.x * 32;
  if (cb >= C) return;
  const float qscale = scale[0];
  __shared__ float tile[32][33];
  int tx = threadIdx.x & 31, ty = threadIdx.x >> 5;  // 32 x 8
  int rb = blockIdx.y * 32;
#pragma unroll
  for (int j = 0; j < 32; j += 8)
    tile[ty + j][tx] = src[(size_t)(rb + ty + j) * C + cb + tx];
  __syncthreads();
#pragma unroll
  for (int j = 0; j < 32; j += 8) {
    int c = cb + ty + j;
    float sc = (c < qcols) ? qscale : 1.0f;
    dst[(size_t)c * R + rb + tx] = f2bf(tile[tx][ty + j] * sc);
  }
}

// ------- 256x192 4-phase GEMM for qkv: grid 512 = EXACTLY 2 full CU rounds ----------
// 8 waves (2M x 4N), per-wave 128x48 (acc[8][3]), BK=64, dbuf 112KB LDS. Stage ops (7)
// front-loaded into phases 0-1; tile-boundary drain keeps 2-phase slack.
// V-cols (>=2048) -> vT transposed.
extern __shared__ char dsmem[];
#define GBUF 57344   // 32KB A + 24KB B per buffer

__global__ __launch_bounds__(512, 2) void gemm256(
    const u16* __restrict__ A0, const u16* __restrict__ A1,
    const u16* __restrict__ B0, const u16* __restrict__ B1,
    u16* __restrict__ Q0, u16* __restrict__ Q1,
    u16* __restrict__ V0, u16* __restrict__ V1) {
  const int orig = blockIdx.x;
  const int wgid = (orig & 7) * 64 + (orig >> 3);    // XCD swizzle (512 % 8 == 0)
  const int z = wgid / 256, rr_ = wgid % 256;
  const int bx = rr_ / 16, by = rr_ % 16;
  const u16* Ag = z ? A1 : A0;
  const u16* Bg = z ? B1 : B0;
  const size_t m0 = (size_t)bx * 256, n0 = (size_t)by * 192;
  const int K = 1024;

  const int tid = threadIdx.x;
  const int lane = tid & 63;
  const int wave = tid >> 6;
  const int wm = wave >> 2, wn = wave & 3;   // 2 x 4; per-wave 128M x 48N
  const int lr = lane & 15, lk = lane >> 4;

  f32x4 acc[8][3] = {};

  auto STG = [&](int buf, int kt, int opi) {
    int idx = opi * 512 + tid;
    char* base = dsmem + buf * GBUF;
    if (idx < 2048) {
      int r = idx >> 3, c = idx & 7;
      gld16(Ag + (m0 + r) * (size_t)K + kt * 64 + ((c ^ (r & 7)) * 8), base + idx * 16);
    } else {
      int j = idx - 2048;
      int r = j >> 3, c = j & 7;
      gld16(Bg + (n0 + r) * (size_t)K + kt * 64 + ((c ^ (r & 7)) * 8), base + 32768 + j * 16);
    }
  };
  auto DSA = [&](short8* af, int buf, int mg, int kh) {
#pragma unroll
    for (int i = 0; i < 4; ++i) {
      int row = wm * 128 + (mg * 4 + i) * 16 + lr;
      af[i] = *reinterpret_cast<const short8*>(
          dsmem + buf * GBUF + row * 128 + (((kh * 4 + lk) ^ (row & 7)) * 16));
    }
  };
  auto DSB = [&](short8* bf_, int buf, int kh) {
#pragma unroll
    for (int j = 0; j < 3; ++j) {
      int row = wn * 48 + j * 16 + lr;
      bf_[j] = *reinterpret_cast<const short8*>(
          dsmem + buf * GBUF + 32768 + row * 128 + (((kh * 4 + lk) ^ (row & 7)) * 16));
    }
  };

#pragma unroll
  for (int o = 0; o < 7; ++o) STG(0, 0, o);
  asm volatile("s_waitcnt vmcnt(0)" ::: "memory");
  __syncthreads();

  int cur = 0;
  for (int kt = 0; kt < 16; ++kt) {
    short8 af[4], bf_[3];
    const int more = (kt < 15);

    // ---- phase 0: (kh0, mg0); stage ops 0-3
    DSA(af, cur, 0, 0); DSB(bf_, cur, 0);
    if (more) { STG(cur ^ 1, kt + 1, 0); STG(cur ^ 1, kt + 1, 1);
                STG(cur ^ 1, kt + 1, 2); STG(cur ^ 1, kt + 1, 3); }
    __builtin_amdgcn_s_barrier();
    asm volatile("s_waitcnt lgkmcnt(0)" ::: "memory");
    __builtin_amdgcn_sched_barrier(0);
    __builtin_amdgcn_s_setprio(1);
#pragma unroll
    for (int i = 0; i < 4; ++i)
#pragma unroll
      for (int j = 0; j < 3; ++j)
        acc[i][j] = __builtin_amdgcn_mfma_f32_16x16x32_bf16(af[i], bf_[j], acc[i][j], 0, 0, 0);
    __builtin_amdgcn_s_setprio(0);
    __builtin_amdgcn_s_barrier();

    // ---- phase 1: (kh0, mg1); B reused; stage ops 4-6
    DSA(af, cur, 1, 0);
    if (more) { STG(cur ^ 1, kt + 1, 4); STG(cur ^ 1, kt + 1, 5);
                STG(cur ^ 1, kt + 1, 6); }
    __builtin_amdgcn_s_barrier();
    asm volatile("s_waitcnt lgkmcnt(0)" ::: "memory");
    __builtin_amdgcn_sched_barrier(0);
    __builtin_amdgcn_s_setprio(1);
#pragma unroll
    for (int i = 0; i < 4; ++i)
#pragma unroll
      for (int j = 0; j < 3; ++j)
        acc[4 + i][j] = __builtin_amdgcn_mfma_f32_16x16x32_bf16(af[i], bf_[j], acc[4 + i][j], 0, 0, 0);
    __builtin_amdgcn_s_setprio(0);
    __builtin_amdgcn_s_barrier();

    // ---- phase 2: (kh1, mg0); no stage
    DSA(af, cur, 0, 1); DSB(bf_, cur, 1);
    __builtin_amdgcn_s_barrier();
    asm volatile("s_waitcnt lgkmcnt(0)" ::: "memory");
    __builtin_amdgcn_sched_barrier(0);
    __builtin_amdgcn_s_setprio(1);
#pragma unroll
    for (int i = 0; i < 4; ++i)
#pragma unroll
      for (int j = 0; j < 3; ++j)
        acc[i][j] = __builtin_amdgcn_mfma_f32_16x16x32_bf16(af[i], bf_[j], acc[i][j], 0, 0, 0);
    __builtin_amdgcn_s_setprio(0);
    __builtin_amdgcn_s_barrier();

    // ---- phase 3: (kh1, mg1); tile-boundary drain (youngest load 2 phases old)
    DSA(af, cur, 1, 1);
    __builtin_amdgcn_s_barrier();
    asm volatile("s_waitcnt lgkmcnt(0)" ::: "memory");
    __builtin_amdgcn_sched_barrier(0);
    __builtin_amdgcn_s_setprio(1);
#pragma unroll
    for (int i = 0; i < 4; ++i)
#pragma unroll
      for (int j = 0; j < 3; ++j)
        acc[4 + i][j] = __builtin_amdgcn_mfma_f32_16x16x32_bf16(af[i], bf_[j], acc[4 + i][j], 0, 0, 0);
    __builtin_amdgcn_s_setprio(0);
    asm volatile("s_waitcnt vmcnt(0)" ::: "memory");
    __builtin_amdgcn_s_barrier();
    cur ^= 1;
  }

  // epilogue: per-frag (16-aligned, wave-uniform) branch: Q/K cols -> qkv row-major;
  // V cols (>=2048) -> vT col-major.
  const int row0 = (int)m0 + wm * 128;
  const int col0 = (int)n0 + wn * 48;
  u16* Qo = z ? Q1 : Q0;
  u16* Vo = z ? V1 : V0;
#pragma unroll
  for (int nf = 0; nf < 3; ++nf) {
    int colf = col0 + nf * 16;          // frag col base, multiple of 16
    if (colf < 2048) {
      int col = colf + lr;
#pragma unroll
      for (int mf = 0; mf < 8; ++mf)
#pragma unroll
        for (int g = 0; g < 4; ++g) {
          int row = row0 + mf * 16 + lk * 4 + g;
          Qo[(size_t)row * 3072 + col] = f2bf(acc[mf][nf][g]);
        }
    } else {
      int col = colf + lr;
#pragma unroll
      for (int mf = 0; mf < 8; ++mf) {
        int row = row0 + mf * 16 + lk * 4;
        size_t vbase = ((size_t)((row >> 11) * 1024 + (col - 2048))) * 2048 + (row & 2047);
        union { u16 s[4]; unsigned long long v; } pk;
#pragma unroll
        for (int g = 0; g < 4; ++g) pk.s[g] = f2bf(acc[mf][nf][g]);
        *reinterpret_cast<unsigned long long*>(Vo + vbase) = pk.v;
      }
    }
  }
}

// ---- out-proj GEMM: 256x128 tiles, grid 256 = EXACTLY 1 CU round, fp32+bias out ----
__global__ __launch_bounds__(512, 2) void gemm_op(
    const u16* __restrict__ A0, const u16* __restrict__ A1,
    const u16* __restrict__ B0, const u16* __restrict__ B1,
    float* __restrict__ C0, float* __restrict__ C1,
    const float* __restrict__ b0_, const float* __restrict__ b1_) {
  const int orig = blockIdx.x;
  const int wgid = (orig & 7) * 32 + (orig >> 3);    // XCD swizzle (256 % 8 == 0)
  const int z = wgid / 128, rr_ = wgid % 128;
  const int bx = rr_ / 8, by = rr_ % 8;
  const u16* Ag = z ? A1 : A0;
  const u16* Bg = z ? B1 : B0;
  float* Cf = z ? C1 : C0;
  const float* bias = z ? b1_ : b0_;
  const size_t m0 = (size_t)bx * 256, n0 = (size_t)by * 128;
  const int K = 1024;

  const int tid = threadIdx.x;
  const int lane = tid & 63;
  const int wave = tid >> 6;
  const int wm = wave >> 1, wn = wave & 1;   // 4 x 2
  const int lr = lane & 15, lk = lane >> 4;

  f32x4 acc[4][4] = {};

  auto STG = [&](int buf, int kt, int opi) {
    int idx = opi * 512 + tid;
    char* base = dsmem + buf * 49152;
    if (idx < 2048) {
      int r = idx >> 3, c = idx & 7;
      gld16(Ag + (m0 + r) * (size_t)K + kt * 64 + ((c ^ (r & 7)) * 8), base + idx * 16);
    } else {
      int j = idx - 2048;
      int r = j >> 3, c = j & 7;
      gld16(Bg + (n0 + r) * (size_t)K + kt * 64 + ((c ^ (r & 7)) * 8), base + 32768 + j * 16);
    }
  };
  auto DSA = [&](short8* af, int buf, int kh) {
#pragma unroll
    for (int i = 0; i < 4; ++i) {
      int row = wm * 64 + i * 16 + lr;
      af[i] = *reinterpret_cast<const short8*>(
          dsmem + buf * 49152 + row * 128 + (((kh * 4 + lk) ^ (row & 7)) * 16));
    }
  };
  auto DSB = [&](short8* bf_, int buf, int kh) {
#pragma unroll
    for (int j = 0; j < 4; ++j) {
      int row = wn * 64 + j * 16 + lr;
      bf_[j] = *reinterpret_cast<const short8*>(
          dsmem + buf * 49152 + 32768 + row * 128 + (((kh * 4 + lk) ^ (row & 7)) * 16));
    }
  };

#pragma unroll
  for (int o = 0; o < 6; ++o) STG(0, 0, o);
  asm volatile("s_waitcnt vmcnt(0)" ::: "memory");
  __syncthreads();

  int cur = 0;
  for (int kt = 0; kt < 16; ++kt) {
    short8 af[4], bf_[4];
    const int more = (kt < 15);

    // ---- phase 0 (kh0); stage ALL 6 next-tile ops
    DSA(af, cur, 0); DSB(bf_, cur, 0);
    if (more) { STG(cur ^ 1, kt + 1, 0); STG(cur ^ 1, kt + 1, 1); STG(cur ^ 1, kt + 1, 2);
                STG(cur ^ 1, kt + 1, 3); STG(cur ^ 1, kt + 1, 4); STG(cur ^ 1, kt + 1, 5); }
    __builtin_amdgcn_s_barrier();
    asm volatile("s_waitcnt lgkmcnt(0)" ::: "memory");
    __builtin_amdgcn_sched_barrier(0);
    __builtin_amdgcn_s_setprio(1);
#pragma unroll
    for (int i = 0; i < 4; ++i)
#pragma unroll
      for (int j = 0; j < 4; ++j)
        acc[i][j] = __builtin_amdgcn_mfma_f32_16x16x32_bf16(af[i], bf_[j], acc[i][j], 0, 0, 0);
    __builtin_amdgcn_s_setprio(0);
    __builtin_amdgcn_s_barrier();

    // ---- phase 1 (kh1); no stage; end-of-tile drain (loads ~1 full phase old)
    DSA(af, cur, 1); DSB(bf_, cur, 1);
    __builtin_amdgcn_s_barrier();
    asm volatile("s_waitcnt lgkmcnt(0)" ::: "memory");
    __builtin_amdgcn_sched_barrier(0);
    __builtin_amdgcn_s_setprio(1);
#pragma unroll
    for (int i = 0; i < 4; ++i)
#pragma unroll
      for (int j = 0; j < 4; ++j)
        acc[i][j] = __builtin_amdgcn_mfma_f32_16x16x32_bf16(af[i], bf_[j], acc[i][j], 0, 0, 0);
    __builtin_amdgcn_s_setprio(0);
    asm volatile("s_waitcnt vmcnt(0)" ::: "memory");
    __builtin_amdgcn_s_barrier();
    cur ^= 1;
  }

  const int row0 = (int)m0 + wm * 64;
  const int col0 = (int)n0 + wn * 64;
#pragma unroll
  for (int nf = 0; nf < 4; ++nf) {
    int col = col0 + nf * 16 + lr;
    float bv = bias[col];
#pragma unroll
    for (int mf = 0; mf < 4; ++mf)
#pragma unroll
      for (int g = 0; g < 4; ++g) {
        int row = row0 + mf * 16 + lk * 4 + g;
        Cf[(size_t)row * 1024 + col] = acc[mf][nf][g] + bv;
      }
  }
}

// -------- flash attention: swapped 32x32, static-max, q64/wave, 1-barrier pipeline ----
// R10/R13-exact schedule (measured 81.5-82.0us across three rounds): KVBLK=64, static
// LDS, per-element hw_exp. KVBLK=128 (R14) and exp-batching (R11) both REGRESSED.
#define KOFF0 0
#define VOFF0 (8192 + 64)
#define KOFF1 (16384 + 128)
#define VOFF1 (KOFF1 + 8192 + 64)

__global__ __launch_bounds__(256, 2) void flash(
    const u16* __restrict__ qkv1, const u16* __restrict__ qkv2,
    const u16* __restrict__ vT1, const u16* __restrict__ vT2,
    u16* __restrict__ ao1, u16* __restrict__ ao2,
    const float* __restrict__ sflag) {
  const int bid = blockIdx.x;
  const int bh_dir = bid & 63;        // XCD selector: bid%8 fixed per (dir,bh)
  const int qt = bid >> 6;            // 0..7 (256 q-rows per block)
  const int dir = bh_dir >> 5;
  const int bh = bh_dir & 31;         // b*16+h
  const int b = bh >> 4, h = bh & 15;
  const u16* qkvQ  = dir ? qkv1 : qkv2;
  const u16* qkvKV = dir ? qkv2 : qkv1;
  const u16* vT    = dir ? vT2 : vT1;
  u16* Oout        = dir ? ao2 : ao1;

  const bool nat = (sflag[1] != 0.0f);   // wave-uniform

  __shared__ __align__(16) char smem[33024];

  const int tid = threadIdx.x;
  const int lane = tid & 63, wave = tid >> 6;
  const int l31 = lane & 31, hi = lane >> 5;

  const int qbase = qt * 256 + wave * 64;
  const u16* qp0 = qkvQ + (size_t)(b * 2048 + qbase + l31) * 3072 + h * 64 + hi * 8;
  const u16* qp1 = qp0 + (size_t)32 * 3072;
  short8 qf0[4], qf1[4];
#pragma unroll
  for (int c = 0; c < 4; ++c) {
    qf0[c] = *reinterpret_cast<const short8*>(qp0 + c * 16);
    qf1[c] = *reinterpret_cast<const short8*>(qp1 + c * 16);
  }

  auto STAGE = [&](char* kb, char* vb, int kv0) {
#pragma unroll
    for (int i = 0; i < 2; ++i) {
      int idx = tid + i * 256;
      int r = idx >> 3, c = idx & 7, cs = c ^ (r & 7);
      gld16(qkvKV + (size_t)(b * 2048 + kv0 + r) * 3072 + 1024 + h * 64 + cs * 8, kb + idx * 16);
      gld16(vT + (size_t)(bh * 64 + r) * 2048 + kv0 + cs * 8, vb + idx * 16);
    }
  };

  auto EXPV = [&](f32x16& S) {
    if (nat) {
#pragma unroll
      for (int r = 0; r < 16; ++r) S[r] = hw_exp(S[r]);
    } else {
#pragma unroll
      for (int r = 0; r < 16; ++r) S[r] = __builtin_exp2f(S[r]);
    }
  };

  short8 ones;                        // bf16 1.0 for the l-sum MFMA
#pragma unroll
  for (int j = 0; j < 8; ++j) ones[j] = (short)0x3F80;

  f32x16 oA0 = {}, oA1 = {}, oB0 = {}, oB1 = {}, laccA = {}, laccB = {};

  STAGE(smem + KOFF0, smem + VOFF0, 0);

  union U8 { unsigned u[4]; short8 s8; };

  for (int t = 0; t < 32; ++t) {
    char* Ks = smem + ((t & 1) ? KOFF1 : KOFF0);
    char* Vs = smem + ((t & 1) ? VOFF1 : VOFF0);
    __syncthreads();                  // drains own DMA for buf(t); all quarters visible
    if (t < 31)
      STAGE(smem + ((t & 1) ? KOFF0 : KOFF1), smem + ((t & 1) ? VOFF0 : VOFF1), (t + 1) * 64);

    // K frags (8 reads, reused by both q-sets). A-operand: m=kv, k=d
    short8 kf[8];
#pragma unroll
    for (int c = 0; c < 4; ++c) {
      int sw = ((c * 2 + hi) ^ (l31 & 7)) * 16;
      kf[c]     = *reinterpret_cast<const short8*>(Ks + l31 * 128 + sw);
      kf[c + 4] = *reinterpret_cast<const short8*>(Ks + (32 + l31) * 128 + sw);
    }

    // QK set0
    f32x16 sA0 = {}, sA1 = {};
#pragma unroll
    for (int c = 0; c < 4; ++c) {
      sA0 = __builtin_amdgcn_mfma_f32_32x32x16_bf16(kf[c],     qf0[c], sA0, 0, 0, 0);
      sA1 = __builtin_amdgcn_mfma_f32_32x32x16_bf16(kf[c + 4], qf0[c], sA1, 0, 0, 0);
    }
    EXPV(sA0); EXPV(sA1);
    short8 paA[4];
#pragma unroll
    for (int kc = 0; kc < 4; ++kc) {
      const f32x16& S = (kc < 2) ? sA0 : sA1;
      int rb = (kc & 1) * 8;
      unsigned a0 = cvtpk(S[rb + 0], S[rb + 1]);
      unsigned b0 = cvtpk(S[rb + 4], S[rb + 5]);
      asm volatile("v_permlane32_swap_b32 %0, %1" : "+v"(a0), "+v"(b0));
      unsigned a1 = cvtpk(S[rb + 2], S[rb + 3]);
      unsigned b1 = cvtpk(S[rb + 6], S[rb + 7]);
      asm volatile("v_permlane32_swap_b32 %0, %1" : "+v"(a1), "+v"(b1));
      U8 u; u.u[0] = a0; u.u[1] = a1; u.u[2] = b0; u.u[3] = b1;
      paA[kc] = u.s8;
    }

    // QK set1 (kf reused, then dead)
    f32x16 sB0 = {}, sB1 = {};
#pragma unroll
    for (int c = 0; c < 4; ++c) {
      sB0 = __builtin_amdgcn_mfma_f32_32x32x16_bf16(kf[c],     qf1[c], sB0, 0, 0, 0);
      sB1 = __builtin_amdgcn_mfma_f32_32x32x16_bf16(kf[c + 4], qf1[c], sB1, 0, 0, 0);
    }

    // V frags (8 reads, reused by both q-sets). B-operand: n=d, k=kv
    short8 vf[8];
#pragma unroll
    for (int kc = 0; kc < 4; ++kc) {
      int sw = ((kc * 2 + hi) ^ (l31 & 7)) * 16;
      vf[kc]     = *reinterpret_cast<const short8*>(Vs + l31 * 128 + sw);
      vf[kc + 4] = *reinterpret_cast<const short8*>(Vs + (32 + l31) * 128 + sw);
    }

    EXPV(sB0); EXPV(sB1);
    short8 paB[4];
#pragma unroll
    for (int kc = 0; kc < 4; ++kc) {
      const f32x16& S = (kc < 2) ? sB0 : sB1;
      int rb = (kc & 1) * 8;
      unsigned a0 = cvtpk(S[rb + 0], S[rb + 1]);
      unsigned b0 = cvtpk(S[rb + 4], S[rb + 5]);
      asm volatile("v_permlane32_swap_b32 %0, %1" : "+v"(a0), "+v"(b0));
      unsigned a1 = cvtpk(S[rb + 2], S[rb + 3]);
      unsigned b1 = cvtpk(S[rb + 6], S[rb + 7]);
      asm volatile("v_permlane32_swap_b32 %0, %1" : "+v"(a1), "+v"(b1));
      U8 u; u.u[0] = a0; u.u[1] = a1; u.u[2] = b0; u.u[3] = b1;
      paB[kc] = u.s8;
    }

    // PV + l-sum (V frags reused across q-sets)
#pragma unroll
    for (int kc = 0; kc < 4; ++kc) {
      oA0 = __builtin_amdgcn_mfma_f32_32x32x16_bf16(paA[kc], vf[kc],     oA0, 0, 0, 0);
      oA1 = __builtin_amdgcn_mfma_f32_32x32x16_bf16(paA[kc], vf[kc + 4], oA1, 0, 0, 0);
      oB0 = __builtin_amdgcn_mfma_f32_32x32x16_bf16(paB[kc], vf[kc],     oB0, 0, 0, 0);
      oB1 = __builtin_amdgcn_mfma_f32_32x32x16_bf16(paB[kc], vf[kc + 4], oB1, 0, 0, 0);
      laccA = __builtin_amdgcn_mfma_f32_32x32x16_bf16(paA[kc], ones, laccA, 0, 0, 0);
      laccB = __builtin_amdgcn_mfma_f32_32x32x16_bf16(paB[kc], ones, laccB, 0, 0, 0);
    }
  }

  // epilogue: lacc[r] = row-sum for output row crow(r,hi) -> no shuffles
  const int rowbase = b * 2048 + qt * 256 + wave * 64;
#pragma unroll
  for (int r = 0; r < 16; ++r) {
    int q = (r & 3) + 8 * (r >> 2) + 4 * hi;
    float liA = 1.0f / laccA[r], liB = 1.0f / laccB[r];
    u16* opA = Oout + (size_t)(rowbase + q) * 1024 + h * 64 + l31;
    u16* opB = opA + (size_t)32 * 1024;
    opA[0]  = f2bf(oA0[r] * liA);
    opA[32] = f2bf(oA1[r] * liA);
    opB[0]  = f2bf(oB0[r] * liB);
    opB[32] = f2bf(oB1[r] * liB);
  }
}

// ------------------------------- host -------------------------------
extern "C" void kernel_launch(void* const* d_in, const int* in_sizes, int n_in,
                              void* d_out, int out_size, void* d_ws, size_t ws_size,
                              hipStream_t stream) {
  const float* x1  = (const float*)d_in[0];
  const float* x2  = (const float*)d_in[1];
  const float* Wq1 = (const float*)d_in[2];
  const float* Wq2 = (const float*)d_in[3];
  const float* Wo1 = (const float*)d_in[4];
  const float* bo1 = (const float*)d_in[5];
  const float* Wo2 = (const float*)d_in[6];
  const float* bo2 = (const float*)d_in[7];
  float* out = (float*)d_out;

  char* ws = (char*)d_ws;
  u16* x1b  = (u16*)(ws + 0);            // 8.0 MB  [4096][1024]
  u16* x2b  = (u16*)(ws + 8388608);
  u16* Wq1t = (u16*)(ws + 16777216);     // 6.0 MB  [3072][1024]
  u16* Wq2t = (u16*)(ws + 23068672);
  u16* Wo1t = (u16*)(ws + 29360128);     // 2.0 MB  [1024][1024]
  u16* Wo2t = (u16*)(ws + 31457280);
  u16* qkv1 = (u16*)(ws + 33554432);     // 24 MB   [4096][3072] (V cols >=2048 unused)
  u16* qkv2 = (u16*)(ws + 58720256);
  u16* vT1  = (u16*)(ws + 83886080);     // 8.0 MB  [32*64][2048]
  u16* vT2  = (u16*)(ws + 92274688);
  u16* ao1  = (u16*)(ws + 100663296);    // 8.0 MB  [4096][1024]
  u16* ao2  = (u16*)(ws + 109051904);    // end: 117440512 (112 MB)

  // scale buffer in qkv1's never-written V-columns (row 0, cols 2048..):
  float* scale_buf = (float*)(qkv1 + 2048);

  hipFuncSetAttribute(reinterpret_cast<const void*>(gemm256),
                      hipFuncAttributeMaxDynamicSharedMemorySize, 114688);
  hipFuncSetAttribute(reinterpret_cast<const void*>(gemm_op),
                      hipFuncAttributeMaxDynamicSharedMemorySize, 98304);

  conv_f32_bf16<<<dim3(2048, 1, 2), 256, 0, stream>>>(x1, x2, x1b, x2b, 4194304 / 8,
                                                      scale_buf);
  transpose_w<<<dim3(96, 32, 4), 256, 0, stream>>>(Wq1, Wq2, Wo1, Wo2,
                                                   Wq1t, Wq2t, Wo1t, Wo2t, scale_buf);

  gemm256<<<dim3(512), 512, 114688, stream>>>(x1b, x2b, Wq1t, Wq2t,
                                              qkv1, qkv2, vT1, vT2);

  flash<<<dim3(512), 256, 0, stream>>>(qkv1, qkv2, vT1, vT2, ao1, ao2, scale_buf);

  gemm_op<<<dim3(256), 512, 98304, stream>>>(ao1, ao2, Wo1t, Wo2t,
                                             out, out + 4194304, bo1, bo2);
}